// Round 5
// baseline (168.685 us; speedup 1.0000x reference)
//
#include <hip/hip_runtime.h>
#include <stdint.h>

// FaceWeightedFusion: B=4, H=W=1024, N=262144, all fp32 in/out.
// Erosion collapsed to capped L-inf distance transform (binary mask):
//   weight(p) = 0 (mask=0) | table[min(15,(d-1)/3)], table[k]=0.1+0.06k (k=15 -> 1.0)
// Kernel A (fused DT): per 64x64 tile,
//   phase 1: row DT for the 156-row halo via 3 ballots/row (zero-bitmaps) ->
//            LDS u8 [col][row], stride 156 (39 words, odd -> conflict-free).
//   phase 2: column envelope D = min_dy max(|dy|, r(y+dy)) via v_pk_{max,min}_i16,
//            window read from LDS; fused 4B/px packed write:
//            bits[0:19] depth*1048575 fixed, [20:24] bucket (31=mask0), [25] edge.
//            Per-batch packed image = 4 MB = one XCD L2.
// Kernel B (sample): 4 points/thread (16 gathers in flight), XCD-affinity
//   swizzle (blockIdx%4 == batch), dwordx4 nt streams.
// ws: packed path needs 16 MB at d_ws. Fallback (<16MB): 3-kernel u8 path (8 MB).

#define HH 1024
#define WW 1024
#define HWIMG (HH * WW)
#define NPTS 262144
#define LSTR 156   // LDS column stride (bytes); 156/4=39 words, odd -> no conflicts

typedef short short2v __attribute__((ext_vector_type(2)));
typedef float f32x4 __attribute__((ext_vector_type(4)));

static __device__ __forceinline__ uint32_t umin_(uint32_t a, uint32_t b) { return a < b ? a : b; }

// ---------------- Kernel A: fused row+column DT + pack ----------------
__global__ __launch_bounds__(256) void fused_dt_kernel(const float* __restrict__ mask,
                                                       const float* __restrict__ edge,
                                                       const float* __restrict__ depth,
                                                       uint32_t* __restrict__ packed_out) {
    __shared__ uint8_t lds[64 * LSTR];
    const int bx = blockIdx.x;
    const int b = bx & 3;                    // batch == XCD affinity group
    const int tile = bx >> 2;                // 0..255
    const int tx = tile & 15, ty = tile >> 4;
    const int x0 = tx * 64, y0 = ty * 64;
    const int c = threadIdx.x & 63;          // lane = column within tile
    const int t = threadIdx.x >> 6;          // wave id (uniform)

    const float* mimg = mask + (size_t)b * HWIMG;

    // ---- phase 1: row DT for halo rows [y0-46, y0+109] (156 rows) ----
    for (int r = t; r < 156; r += 4) {
        const int y = y0 - 46 + r;
        uint32_t d = 46;
        if (y >= 0 && y < HH) {
            const float* mrow = mimg + (size_t)y * WW;
            uint64_t W0 = 0, W1, W2 = 0;
            W1 = __ballot(mrow[x0 + c] == 0.0f);
            if (x0 > 0)        W0 = __ballot(mrow[x0 - 64 + c] == 0.0f);
            if (x0 < WW - 64)  W2 = __ballot(mrow[x0 + 64 + c] == 0.0f);
            uint64_t rmask = (W1 >> c) | ((W2 << 1) << (63 - c));
            uint64_t lmask = (W1 << (63 - c)) | ((W0 >> 1) >> c);
            int dr = rmask ? __builtin_ctzll(rmask) : 64;
            int dl = lmask ? __builtin_clzll(lmask) : 64;
            int dd = dr < dl ? dr : dl;
            d = dd > 46 ? 46u : (uint32_t)dd;
        }
        lds[c * LSTR + r] = (uint8_t)d;
    }
    __syncthreads();

    // ---- phase 2: column envelope from LDS window, fused pack ----
    const int ybase = y0 + t * 16;
    const uint8_t* colp = lds + c * LSTR + t * 16;   // window starts at ybase-46 == LDS row t*16
    uint32_t win[54];
#pragma unroll
    for (int j = 0; j < 54; ++j) {
        uint32_t v = *(const uint16_t*)(colp + 2 * j);     // (r_2j, r_2j+1), 2B aligned
        win[j] = (v & 0xffu) | ((v & 0xff00u) << 8);       // -> (i16, i16)
    }

#pragma unroll
    for (int i = 0; i < 16; ++i) {
        const int base = i >> 1;
        const int par = i & 1;
        short2v D2 = (short2v){46, 46};
#pragma unroll
        for (int q = 0; q < 47; ++q) {
            int dy0 = 2 * q - 46 - par;                 // compile-time
            short a0 = (short)(dy0 < 0 ? -dy0 : dy0);
            short a1 = (short)(dy0 + 1 < 0 ? -(dy0 + 1) : dy0 + 1);
            short2v A = (short2v){a0, a1};
            short2v v = __builtin_bit_cast(short2v, win[base + q]);
            short2v mx = __builtin_elementwise_max(A, v);   // v_pk_max_i16
            D2 = __builtin_elementwise_min(D2, mx);         // v_pk_min_i16
        }
        uint32_t D = (uint32_t)(D2.x < D2.y ? D2.x : D2.y);
        const size_t pix = (size_t)b * HWIMG + (size_t)(ybase + i) * WW + x0 + c;
        float dv = __builtin_nontemporal_load(&depth[pix]);
        float ev = __builtin_nontemporal_load(&edge[pix]);   // exactly 0.0f/1.0f
        uint32_t q20 = (uint32_t)fminf(rintf(dv * 1048575.0f), 1048575.0f);
        uint32_t bk = (D == 0) ? 31u : umin_(15u, (D - 1u) / 3u);
        uint32_t word = q20 | (bk << 20) | ((ev != 0.0f ? 1u : 0u) << 25);
        __builtin_nontemporal_store(word, &packed_out[pix]);
    }
}

// ---------------- Kernel B: sampling, 4 points/thread ----------------
static __device__ __forceinline__ float decode_w5(uint32_t p) {
    uint32_t k = (p >> 20) & 31u;
    if (k == 31u) return 0.0f;
    float v = 0.1f + (float)k * 0.06f;
    return v < 1.0f ? v : 1.0f;
}

__global__ __launch_bounds__(256) void sample4_kernel(
    const uint32_t* __restrict__ pimg, const float* __restrict__ xy,
    const float* __restrict__ z, const float* __restrict__ occ_body,
    const float* __restrict__ occ_face, float* __restrict__ out) {
    const int b = blockIdx.x & 3;            // XCD affinity: one 4MB image per XCD L2
    const int n0 = (blockIdx.x >> 2) * 1024 + threadIdx.x * 4;
    const size_t pb = (size_t)b * NPTS;

    f32x4 xv  = __builtin_nontemporal_load((const f32x4*)&xy[pb * 2 + n0]);
    f32x4 yv  = __builtin_nontemporal_load((const f32x4*)&xy[pb * 2 + NPTS + n0]);
    f32x4 zv  = __builtin_nontemporal_load((const f32x4*)&z[pb + n0]);
    f32x4 obv = __builtin_nontemporal_load((const f32x4*)&occ_body[pb + n0]);
    f32x4 ofv = __builtin_nontemporal_load((const f32x4*)&occ_face[pb + n0]);

    const uint32_t* img = pimg + (size_t)b * HWIMG;
    f32x4 res;
    size_t idx[4][4];
    float wgt[4][4];
#pragma unroll
    for (int j = 0; j < 4; ++j) {
        float fx = ((xv[j] + 1.0f) * 0.5f) * 1023.0f;
        float fy = ((yv[j] + 1.0f) * 0.5f) * 1023.0f;
        float x0f = floorf(fx), y0f = floorf(fy);
        float wx = fx - x0f, wy = fy - y0f;
        int x0i = (int)x0f; x0i = x0i < 0 ? 0 : (x0i > 1023 ? 1023 : x0i);
        int y0i = (int)y0f; y0i = y0i < 0 ? 0 : (y0i > 1023 ? 1023 : y0i);
        int x1i = x0i + 1 > 1023 ? 1023 : x0i + 1;
        int y1i = y0i + 1 > 1023 ? 1023 : y0i + 1;
        idx[j][0] = (size_t)y0i * WW + x0i;
        idx[j][1] = (size_t)y0i * WW + x1i;
        idx[j][2] = (size_t)y1i * WW + x0i;
        idx[j][3] = (size_t)y1i * WW + x1i;
        wgt[j][0] = (1.0f - wx) * (1.0f - wy);
        wgt[j][1] = wx * (1.0f - wy);
        wgt[j][2] = (1.0f - wx) * wy;
        wgt[j][3] = wx * wy;
    }
    uint32_t pw[4][4];
#pragma unroll
    for (int j = 0; j < 4; ++j)        // 16 independent gathers in flight
#pragma unroll
        for (int k = 0; k < 4; ++k) pw[j][k] = img[idx[j][k]];

#pragma unroll
    for (int j = 0; j < 4; ++j) {
        float e = (float)((pw[j][0] >> 25) & 1u) * wgt[j][0]
                + (float)((pw[j][1] >> 25) & 1u) * wgt[j][1]
                + (float)((pw[j][2] >> 25) & 1u) * wgt[j][2]
                + (float)((pw[j][3] >> 25) & 1u) * wgt[j][3];
        float w = 0.0f;
        if (e > 0.01f) {
            const float DQS = 1.0f / 1048575.0f;
            float dq = ((float)(pw[j][0] & 0xFFFFFu) * wgt[j][0]
                      + (float)(pw[j][1] & 0xFFFFFu) * wgt[j][1]
                      + (float)(pw[j][2] & 0xFFFFFu) * wgt[j][2]
                      + (float)(pw[j][3] & 0xFFFFFu) * wgt[j][3]) * DQS;
            float la = decode_w5(pw[j][0]) * wgt[j][0] + decode_w5(pw[j][1]) * wgt[j][1]
                     + decode_w5(pw[j][2]) * wgt[j][2] + decode_w5(pw[j][3]) * wgt[j][3];
            float ps = zv[j] - dq;
            w = expf(-(ps * ps) * 1000.0f) * la;
        }
        res[j] = w * ofv[j] + (1.0f - w) * obv[j];
    }
    __builtin_nontemporal_store(res, (f32x4*)&out[pb + n0]);
}

// ---------------- Fallback path (tiny ws): 3-kernel u8 pipeline ----------------
__global__ __launch_bounds__(256) void row_dt_kernel(const float* __restrict__ mask,
                                                     uint8_t* __restrict__ rbuf) {
    __shared__ uint64_t words[4][18];
    const int w = threadIdx.x >> 6;
    const int l = threadIdx.x & 63;
    const int row = blockIdx.x * 4 + w;
    const float* mrow = mask + (size_t)row * WW;

    if (l == 0) { words[w][0] = 0ull; words[w][17] = 0ull; }
    for (int i = 0; i < 16; ++i) {
        float m = mrow[i * 64 + l];
        uint64_t bm = __ballot(m == 0.0f);
        if (l == 0) words[w][i + 1] = bm;
    }
    __syncthreads();

    uint8_t* rrow = rbuf + (size_t)row * WW;
    for (int i = 0; i < 16; ++i) {
        uint64_t W0 = words[w][i];
        uint64_t W1 = words[w][i + 1];
        uint64_t W2 = words[w][i + 2];
        uint64_t rmask = (W1 >> l) | ((W2 << 1) << (63 - l));
        uint64_t lmask = (W1 << (63 - l)) | ((W0 >> 1) >> l);
        int dr = rmask ? __builtin_ctzll(rmask) : 64;
        int dl = lmask ? __builtin_clzll(lmask) : 64;
        int d = dr < dl ? dr : dl;
        if (d > 46) d = 46;
        rrow[i * 64 + l] = (uint8_t)d;
    }
}

__global__ __launch_bounds__(256) void col_dt_u8_kernel(const uint8_t* __restrict__ rbuf,
                                                        uint8_t* __restrict__ bucket_out) {
    const int bx = blockIdx.x;
    const int tx = bx & 15, ty = (bx >> 4) & 15, b = bx >> 8;
    const int x0 = tx * 64, y0 = ty * 64;
    const int c = threadIdx.x & 63;
    const int t = threadIdx.x >> 6;
    const int ybase = y0 + t * 16;
    const uint8_t* img = rbuf + (size_t)b * HWIMG + x0 + c;

    uint32_t win[54];
#pragma unroll
    for (int j = 0; j < 54; ++j) {
        int r0 = ybase - 46 + 2 * j;
        int r1 = r0 + 1;
        int r0c = r0 < 0 ? 0 : (r0 > 1023 ? 1023 : r0);
        int r1c = r1 < 0 ? 0 : (r1 > 1023 ? 1023 : r1);
        uint32_t lo = img[(size_t)r0c * WW];
        uint32_t hi = img[(size_t)r1c * WW];
        if (r0 != r0c) lo = 46;
        if (r1 != r1c) hi = 46;
        win[j] = lo | (hi << 16);
    }
#pragma unroll
    for (int i = 0; i < 16; ++i) {
        const int base = i >> 1;
        const int par = i & 1;
        short2v D2 = (short2v){46, 46};
#pragma unroll
        for (int q = 0; q < 47; ++q) {
            int dy0 = 2 * q - 46 - par;
            short a0 = (short)(dy0 < 0 ? -dy0 : dy0);
            short a1 = (short)(dy0 + 1 < 0 ? -(dy0 + 1) : dy0 + 1);
            short2v A = (short2v){a0, a1};
            short2v v = __builtin_bit_cast(short2v, win[base + q]);
            short2v mx = __builtin_elementwise_max(A, v);
            D2 = __builtin_elementwise_min(D2, mx);
        }
        uint32_t D = (uint32_t)(D2.x < D2.y ? D2.x : D2.y);
        uint8_t o = (D == 0) ? (uint8_t)255 : (uint8_t)umin_(15u, (D - 1u) / 3u);
        bucket_out[(size_t)b * HWIMG + (size_t)(ybase + i) * WW + x0 + c] = o;
    }
}

static __device__ __forceinline__ float decode_w8(uint32_t k) {
    if (k == 255u) return 0.0f;
    float v = 0.1f + (float)k * 0.06f;
    return v < 1.0f ? v : 1.0f;
}

__global__ __launch_bounds__(256) void sample_fallback_kernel(
    const float* __restrict__ edge_img, const float* __restrict__ depth_img,
    const uint8_t* __restrict__ wimg,
    const float* __restrict__ xy, const float* __restrict__ z,
    const float* __restrict__ occ_body, const float* __restrict__ occ_face,
    float* __restrict__ out) {
    const int b = blockIdx.x & 3;
    const int n = (blockIdx.x >> 2) * 256 + threadIdx.x;

    float x = xy[(size_t)b * 2 * NPTS + n];
    float y = xy[(size_t)b * 2 * NPTS + NPTS + n];
    float fx = ((x + 1.0f) * 0.5f) * 1023.0f;
    float fy = ((y + 1.0f) * 0.5f) * 1023.0f;
    float x0f = floorf(fx), y0f = floorf(fy);
    float wx = fx - x0f, wy = fy - y0f;
    int x0i = (int)x0f; x0i = x0i < 0 ? 0 : (x0i > 1023 ? 1023 : x0i);
    int y0i = (int)y0f; y0i = y0i < 0 ? 0 : (y0i > 1023 ? 1023 : y0i);
    int x1i = x0i + 1 > 1023 ? 1023 : x0i + 1;
    int y1i = y0i + 1 > 1023 ? 1023 : y0i + 1;

    const size_t base = (size_t)b * HWIMG;
    const size_t i00 = base + (size_t)y0i * WW + x0i;
    const size_t i01 = base + (size_t)y0i * WW + x1i;
    const size_t i10 = base + (size_t)y1i * WW + x0i;
    const size_t i11 = base + (size_t)y1i * WW + x1i;

    const float w00 = (1.0f - wx) * (1.0f - wy);
    const float w01 = wx * (1.0f - wy);
    const float w10 = (1.0f - wx) * wy;
    const float w11 = wx * wy;

    float zv = z[(size_t)b * NPTS + n];
    float ob = occ_body[(size_t)b * NPTS + n];
    float of = occ_face[(size_t)b * NPTS + n];

    float w = 0.0f;
    float e = edge_img[i00] * w00 + edge_img[i01] * w01
            + edge_img[i10] * w10 + edge_img[i11] * w11;
    if (e > 0.01f) {
        float dq = depth_img[i00] * w00 + depth_img[i01] * w01
                 + depth_img[i10] * w10 + depth_img[i11] * w11;
        float la = decode_w8(wimg[i00]) * w00 + decode_w8(wimg[i01]) * w01
                 + decode_w8(wimg[i10]) * w10 + decode_w8(wimg[i11]) * w11;
        float ps = zv - dq;
        w = expf(-(ps * ps) * 1000.0f) * la;
    }
    out[(size_t)b * NPTS + n] = w * of + (1.0f - w) * ob;
}

extern "C" void kernel_launch(void* const* d_in, const int* in_sizes, int n_in,
                              void* d_out, int out_size, void* d_ws, size_t ws_size,
                              hipStream_t stream) {
    const float* mask      = (const float*)d_in[0];
    const float* depth     = (const float*)d_in[1];
    const float* edge      = (const float*)d_in[2];
    const float* xy        = (const float*)d_in[3];
    const float* z         = (const float*)d_in[4];
    const float* occ_body  = (const float*)d_in[5];
    const float* occ_face  = (const float*)d_in[6];
    float* out = (float*)d_out;

    if (ws_size >= (size_t)4 * HWIMG * 4) {           // 16 MB packed path
        uint32_t* pimg = (uint32_t*)d_ws;
        fused_dt_kernel<<<1024, 256, 0, stream>>>(mask, edge, depth, pimg);
        sample4_kernel<<<1024, 256, 0, stream>>>(pimg, xy, z, occ_body, occ_face, out);
    } else {                                          // 8 MB fallback
        uint8_t* rbuf = (uint8_t*)d_ws;
        uint8_t* wbuf = rbuf + (size_t)4 * HWIMG;
        row_dt_kernel<<<1024, 256, 0, stream>>>(mask, rbuf);
        col_dt_u8_kernel<<<1024, 256, 0, stream>>>(rbuf, wbuf);
        sample_fallback_kernel<<<4096, 256, 0, stream>>>(edge, depth, wbuf,
                                                         xy, z, occ_body, occ_face, out);
    }
}

// Round 6
// 137.406 us; speedup vs baseline: 1.2276x; 1.2276x over previous
//
#include <hip/hip_runtime.h>
#include <stdint.h>

// FaceWeightedFusion: B=4, H=W=1024, N=262144, all fp32 in/out.
// Erosion collapsed to capped L-inf distance transform (binary mask):
//   weight(p) = 0 (mask=0) | table[min(15,(d-1)/3)], table[k]=0.1+0.06k (k=15 -> 1.0)
// K1 row_dt: ballot zero-bitmaps + ctz/clz -> u8 row distances (cap 46).
// K2 col_dt: fast +-5 register window via v_pk_{max,min}_i16 (if partial min <= 5
//   it equals the true envelope, since all excluded |dy| >= 5; P(slow) ~ 2^-77 on
//   Bernoulli masks); ballot-guarded exact fallback. Fused 4B/px packed write:
//   [0:19] depth*1048575, [20:24] bucket (31=mask0), [25] edge. 4MB/batch = 1 XCD L2.
// K3 sample4: 4 pts/thread, XCD-affinity (blockIdx%4==batch), paired dwordx2
//   corner gathers (x-adjacent corners share one load), dwordx4 nt streams.
// NOTE R5 lesson: do NOT fuse row into col — 156-row halo recompute + 3x ballots
//   cost ~7x the row-DT work (59us vs 14.5us measured).
// ws: packed path 20 MB. Fallback (<20MB): u8 bucket path.

#define HH 1024
#define WW 1024
#define HWIMG (HH * WW)
#define NPTS 262144

typedef short short2v __attribute__((ext_vector_type(2)));
typedef float f32x4 __attribute__((ext_vector_type(4)));
typedef uint32_t u32x2 __attribute__((ext_vector_type(2), aligned(4)));

static __device__ __forceinline__ uint32_t umin_(uint32_t a, uint32_t b) { return a < b ? a : b; }

// ---------------- Kernel 1: row distance transform (capped 46) ----------------
__global__ __launch_bounds__(256) void row_dt_kernel(const float* __restrict__ mask,
                                                     uint8_t* __restrict__ rbuf) {
    __shared__ uint64_t words[4][18];
    const int w = threadIdx.x >> 6;
    const int l = threadIdx.x & 63;
    const int row = blockIdx.x * 4 + w;   // b*1024 + y
    const float* mrow = mask + (size_t)row * WW;

    if (l == 0) { words[w][0] = 0ull; words[w][17] = 0ull; }
    for (int i = 0; i < 16; ++i) {
        float m = mrow[i * 64 + l];
        uint64_t bm = __ballot(m == 0.0f);
        if (l == 0) words[w][i + 1] = bm;
    }
    __syncthreads();

    uint8_t* rrow = rbuf + (size_t)row * WW;
    for (int i = 0; i < 16; ++i) {
        uint64_t W0 = words[w][i];
        uint64_t W1 = words[w][i + 1];
        uint64_t W2 = words[w][i + 2];
        uint64_t rmask = (W1 >> l) | ((W2 << 1) << (63 - l));
        uint64_t lmask = (W1 << (63 - l)) | ((W0 >> 1) >> l);
        int dr = rmask ? __builtin_ctzll(rmask) : 64;
        int dl = lmask ? __builtin_clzll(lmask) : 64;
        int d = dr < dl ? dr : dl;
        if (d > 46) d = 46;
        rrow[i * 64 + l] = (uint8_t)d;
    }
}

// ------------- Kernel 2: column envelope, +-5 fast window + pack -------------
template<bool PACK>
__global__ __launch_bounds__(256) void col_dt_kernel(const uint8_t* __restrict__ rbuf,
                                                     const float* __restrict__ edge,
                                                     const float* __restrict__ depth,
                                                     uint8_t* __restrict__ bucket_out,
                                                     uint32_t* __restrict__ packed_out) {
    const int bx = blockIdx.x;
    const int tx = bx & 15, ty = (bx >> 4) & 15, b = bx >> 8;
    const int x0 = tx * 64, y0 = ty * 64;
    const int c = threadIdx.x & 63;
    const int t = threadIdx.x >> 6;
    const int ybase = y0 + t * 16;
    const uint8_t* imgc = rbuf + (size_t)b * HWIMG + x0 + c;

    // Fast window: rows [ybase-4, ybase+19] as 12 (even,odd) i16 pairs.
    uint32_t wf[12];
#pragma unroll
    for (int j = 0; j < 12; ++j) {
        int r0 = ybase - 4 + 2 * j;
        int r1 = r0 + 1;
        int r0c = r0 < 0 ? 0 : (r0 > 1023 ? 1023 : r0);
        int r1c = r1 < 0 ? 0 : (r1 > 1023 ? 1023 : r1);
        uint32_t lo = imgc[(size_t)r0c * WW];      // coalesced 64B wave load
        uint32_t hi = imgc[(size_t)r1c * WW];
        if (r0 != r0c) lo = 46;                    // outside image: no zeros
        if (r1 != r1c) hi = 46;
        wf[j] = lo | (hi << 16);
    }

    uint32_t Dv[16];
    bool bad = false;
#pragma unroll
    for (int i = 0; i < 16; ++i) {
        const int base2 = i >> 1;
        const int par = i & 1;
        short2v D2 = (short2v){46, 46};
#pragma unroll
        for (int q = 0; q < 5; ++q) {              // covers dy in [-5,5] (by parity)
            int dy0 = 2 * q - 4 - par;             // compile-time
            short a0 = (short)(dy0 < 0 ? -dy0 : dy0);
            short a1 = (short)(dy0 + 1 < 0 ? -(dy0 + 1) : dy0 + 1);
            short2v A = (short2v){a0, a1};
            short2v v = __builtin_bit_cast(short2v, wf[base2 + q]);
            short2v mx = __builtin_elementwise_max(A, v);   // v_pk_max_i16
            D2 = __builtin_elementwise_min(D2, mx);         // v_pk_min_i16
        }
        uint32_t D = (uint32_t)(D2.x < D2.y ? D2.x : D2.y);
        Dv[i] = D;
        bad |= (D >= 6);       // excluded terms all >= 5 -> partial<=5 is exact
    }

    if (__ballot(bad) != 0) {  // exact fallback, register-light (P ~ 0 on real data)
#pragma unroll
        for (int i = 0; i < 16; ++i) {
            uint32_t D = 46;
            for (int dy = -46; dy <= 46; ++dy) {
                int y = ybase + i + dy;
                uint32_t r = 46;
                if (y >= 0 && y < HH) r = imgc[(size_t)y * WW];
                uint32_t a = (uint32_t)(dy < 0 ? -dy : dy);
                uint32_t m = a > r ? a : r;
                D = D < m ? D : m;
            }
            Dv[i] = D;
        }
    }

#pragma unroll
    for (int i = 0; i < 16; ++i) {
        uint32_t D = Dv[i];
        const size_t pix = (size_t)b * HWIMG + (size_t)(ybase + i) * WW + x0 + c;
        if (PACK) {
            float dv = __builtin_nontemporal_load(&depth[pix]);
            float ev = __builtin_nontemporal_load(&edge[pix]);   // exactly 0.0f/1.0f
            uint32_t q20 = (uint32_t)fminf(rintf(dv * 1048575.0f), 1048575.0f);
            uint32_t bk = (D == 0) ? 31u : umin_(15u, (D - 1u) / 3u);
            uint32_t word = q20 | (bk << 20) | ((ev != 0.0f ? 1u : 0u) << 25);
            __builtin_nontemporal_store(word, &packed_out[pix]);
        } else {
            uint8_t o = (D == 0) ? (uint8_t)255 : (uint8_t)umin_(15u, (D - 1u) / 3u);
            bucket_out[pix] = o;
        }
    }
}

// ---------------- Kernel 3: sampling, 4 points/thread, paired gathers ----------------
static __device__ __forceinline__ float decode_w5(uint32_t p) {
    uint32_t k = (p >> 20) & 31u;
    if (k == 31u) return 0.0f;
    float v = 0.1f + (float)k * 0.06f;
    return v < 1.0f ? v : 1.0f;
}

__global__ __launch_bounds__(256) void sample4_kernel(
    const uint32_t* __restrict__ pimg, const float* __restrict__ xy,
    const float* __restrict__ z, const float* __restrict__ occ_body,
    const float* __restrict__ occ_face, float* __restrict__ out) {
    const int b = blockIdx.x & 3;            // XCD affinity: one 4MB image per XCD L2
    const int n0 = (blockIdx.x >> 2) * 1024 + threadIdx.x * 4;
    const size_t pb = (size_t)b * NPTS;

    f32x4 xv  = __builtin_nontemporal_load((const f32x4*)&xy[pb * 2 + n0]);
    f32x4 yv  = __builtin_nontemporal_load((const f32x4*)&xy[pb * 2 + NPTS + n0]);
    f32x4 zv  = __builtin_nontemporal_load((const f32x4*)&z[pb + n0]);
    f32x4 obv = __builtin_nontemporal_load((const f32x4*)&occ_body[pb + n0]);
    f32x4 ofv = __builtin_nontemporal_load((const f32x4*)&occ_face[pb + n0]);

    const uint32_t* img = pimg + (size_t)b * HWIMG;
    f32x4 res;
    const uint32_t* addr[4][2];
    int sel[4];
    float wgt[4][4];
#pragma unroll
    for (int j = 0; j < 4; ++j) {
        float fx = ((xv[j] + 1.0f) * 0.5f) * 1023.0f;
        float fy = ((yv[j] + 1.0f) * 0.5f) * 1023.0f;
        float x0f = floorf(fx), y0f = floorf(fy);
        float wx = fx - x0f, wy = fy - y0f;
        int x0i = (int)x0f; x0i = x0i < 0 ? 0 : (x0i > 1023 ? 1023 : x0i);
        int y0i = (int)y0f; y0i = y0i < 0 ? 0 : (y0i > 1023 ? 1023 : y0i);
        int y1i = y0i + 1 > 1023 ? 1023 : y0i + 1;
        // x0i==1023 => fx==1023 exactly => wx==0 => x1 value irrelevant. Load the
        // pair at min(x0i,1022); sel shifts so pair[sel]=corner x0, pair[1]=corner x1.
        int xl = x0i > 1022 ? 1022 : x0i;
        sel[j] = x0i - xl;                       // 0 or 1
        addr[j][0] = img + (size_t)y0i * WW + xl;
        addr[j][1] = img + (size_t)y1i * WW + xl;
        wgt[j][0] = (1.0f - wx) * (1.0f - wy);
        wgt[j][1] = wx * (1.0f - wy);
        wgt[j][2] = (1.0f - wx) * wy;
        wgt[j][3] = wx * wy;
    }
    u32x2 pr[4][2];
#pragma unroll
    for (int j = 0; j < 4; ++j) {                // 8 independent dwordx2 gathers
        pr[j][0] = *(const u32x2*)addr[j][0];
        pr[j][1] = *(const u32x2*)addr[j][1];
    }

#pragma unroll
    for (int j = 0; j < 4; ++j) {
        uint32_t p00 = sel[j] ? pr[j][0].y : pr[j][0].x;
        uint32_t p01 = pr[j][0].y;
        uint32_t p10 = sel[j] ? pr[j][1].y : pr[j][1].x;
        uint32_t p11 = pr[j][1].y;
        float e = (float)((p00 >> 25) & 1u) * wgt[j][0]
                + (float)((p01 >> 25) & 1u) * wgt[j][1]
                + (float)((p10 >> 25) & 1u) * wgt[j][2]
                + (float)((p11 >> 25) & 1u) * wgt[j][3];
        float w = 0.0f;
        if (e > 0.01f) {
            const float DQS = 1.0f / 1048575.0f;
            float dq = ((float)(p00 & 0xFFFFFu) * wgt[j][0]
                      + (float)(p01 & 0xFFFFFu) * wgt[j][1]
                      + (float)(p10 & 0xFFFFFu) * wgt[j][2]
                      + (float)(p11 & 0xFFFFFu) * wgt[j][3]) * DQS;
            float la = decode_w5(p00) * wgt[j][0] + decode_w5(p01) * wgt[j][1]
                     + decode_w5(p10) * wgt[j][2] + decode_w5(p11) * wgt[j][3];
            float ps = zv[j] - dq;
            w = expf(-(ps * ps) * 1000.0f) * la;
        }
        res[j] = w * ofv[j] + (1.0f - w) * obv[j];
    }
    __builtin_nontemporal_store(res, (f32x4*)&out[pb + n0]);
}

// ---------------- Fallback sample (tiny ws): 3-image scalar path ----------------
static __device__ __forceinline__ float decode_w8(uint32_t k) {
    if (k == 255u) return 0.0f;
    float v = 0.1f + (float)k * 0.06f;
    return v < 1.0f ? v : 1.0f;
}

__global__ __launch_bounds__(256) void sample_fallback_kernel(
    const float* __restrict__ edge_img, const float* __restrict__ depth_img,
    const uint8_t* __restrict__ wimg,
    const float* __restrict__ xy, const float* __restrict__ z,
    const float* __restrict__ occ_body, const float* __restrict__ occ_face,
    float* __restrict__ out) {
    const int b = blockIdx.x & 3;
    const int n = (blockIdx.x >> 2) * 256 + threadIdx.x;

    float x = xy[(size_t)b * 2 * NPTS + n];
    float y = xy[(size_t)b * 2 * NPTS + NPTS + n];
    float fx = ((x + 1.0f) * 0.5f) * 1023.0f;
    float fy = ((y + 1.0f) * 0.5f) * 1023.0f;
    float x0f = floorf(fx), y0f = floorf(fy);
    float wx = fx - x0f, wy = fy - y0f;
    int x0i = (int)x0f; x0i = x0i < 0 ? 0 : (x0i > 1023 ? 1023 : x0i);
    int y0i = (int)y0f; y0i = y0i < 0 ? 0 : (y0i > 1023 ? 1023 : y0i);
    int x1i = x0i + 1 > 1023 ? 1023 : x0i + 1;
    int y1i = y0i + 1 > 1023 ? 1023 : y0i + 1;

    const size_t base = (size_t)b * HWIMG;
    const size_t i00 = base + (size_t)y0i * WW + x0i;
    const size_t i01 = base + (size_t)y0i * WW + x1i;
    const size_t i10 = base + (size_t)y1i * WW + x0i;
    const size_t i11 = base + (size_t)y1i * WW + x1i;

    const float w00 = (1.0f - wx) * (1.0f - wy);
    const float w01 = wx * (1.0f - wy);
    const float w10 = (1.0f - wx) * wy;
    const float w11 = wx * wy;

    float zv = z[(size_t)b * NPTS + n];
    float ob = occ_body[(size_t)b * NPTS + n];
    float of = occ_face[(size_t)b * NPTS + n];

    float w = 0.0f;
    float e = edge_img[i00] * w00 + edge_img[i01] * w01
            + edge_img[i10] * w10 + edge_img[i11] * w11;
    if (e > 0.01f) {
        float dq = depth_img[i00] * w00 + depth_img[i01] * w01
                 + depth_img[i10] * w10 + depth_img[i11] * w11;
        float la = decode_w8(wimg[i00]) * w00 + decode_w8(wimg[i01]) * w01
                 + decode_w8(wimg[i10]) * w10 + decode_w8(wimg[i11]) * w11;
        float ps = zv - dq;
        w = expf(-(ps * ps) * 1000.0f) * la;
    }
    out[(size_t)b * NPTS + n] = w * of + (1.0f - w) * ob;
}

extern "C" void kernel_launch(void* const* d_in, const int* in_sizes, int n_in,
                              void* d_out, int out_size, void* d_ws, size_t ws_size,
                              hipStream_t stream) {
    const float* mask      = (const float*)d_in[0];
    const float* depth     = (const float*)d_in[1];
    const float* edge      = (const float*)d_in[2];
    const float* xy        = (const float*)d_in[3];
    const float* z         = (const float*)d_in[4];
    const float* occ_body  = (const float*)d_in[5];
    const float* occ_face  = (const float*)d_in[6];
    float* out = (float*)d_out;

    uint8_t* rbuf = (uint8_t*)d_ws;                          // 4 MB
    const size_t need_packed = (size_t)4 * HWIMG + (size_t)4 * HWIMG * 4;  // 20 MB

    row_dt_kernel<<<1024, 256, 0, stream>>>(mask, rbuf);

    if (ws_size >= need_packed) {
        uint32_t* pimg = (uint32_t*)(rbuf + (size_t)4 * HWIMG);  // 16 MB
        col_dt_kernel<true><<<1024, 256, 0, stream>>>(rbuf, edge, depth, nullptr, pimg);
        sample4_kernel<<<1024, 256, 0, stream>>>(pimg, xy, z, occ_body, occ_face, out);
    } else {
        uint8_t* wbuf = rbuf + (size_t)4 * HWIMG;            // 4 MB
        col_dt_kernel<false><<<1024, 256, 0, stream>>>(rbuf, edge, depth, wbuf, nullptr);
        sample_fallback_kernel<<<4096, 256, 0, stream>>>(edge, depth, wbuf,
                                                         xy, z, occ_body, occ_face, out);
    }
}